// Round 13
// baseline (1191.592 us; speedup 1.0000x reference)
//
#include <hip/hip_runtime.h>
#include <hip/hip_fp16.h>

#define B_ 256
#define T_ 512
#define D_ 64
#define H_ 128
#define BB 32  // batches per recurrent block: 2 independent groups of 16

typedef float f32x4 __attribute__((ext_vector_type(4)));
typedef short s16x4 __attribute__((ext_vector_type(4)));
typedef short s16x8 __attribute__((ext_vector_type(8)));
typedef __fp16 fp16x2 __attribute__((ext_vector_type(2)));
typedef _Float16 h16x4 __attribute__((ext_vector_type(4)));
typedef _Float16 f16x8v __attribute__((ext_vector_type(8)));

__device__ unsigned short g_W16[7 * 8 * 2 * 512];  // fp16 frag-ordered weights
__device__ float g_bias[512];                      // [G,z,r,h] biases

__device__ inline float fsig(float x) {
  return __builtin_amdgcn_rcpf(1.f + __expf(-x));
}
__device__ inline float ftanh(float x) {
  return 1.f - 2.f * __builtin_amdgcn_rcpf(1.f + __expf(2.f * x));
}
// fp16 MFMA, both operands as raw 16-bit fragments
__device__ __forceinline__ f32x4 MFH(s16x8 a, s16x8 b, f32x4 c) {
  return __builtin_amdgcn_mfma_f32_16x16x32_f16(
      __builtin_bit_cast(f16x8v, a), __builtin_bit_cast(f16x8v, b), c, 0, 0, 0);
}
__device__ __forceinline__ f32x4 MFH2(s16x8 wfrag, f16x8v xfrag, f32x4 c) {
  return __builtin_amdgcn_mfma_f32_16x16x32_f16(
      __builtin_bit_cast(f16x8v, wfrag), xfrag, c, 0, 0, 0);
}

// Barrier draining ONLY LDS ops: global loads/stores stay in flight.
#define BAR()                                              \
  do {                                                     \
    asm volatile("s_waitcnt lgkmcnt(0)" ::: "memory");     \
    __builtin_amdgcn_s_barrier();                          \
  } while (0)

// ---------------------------------------------------------------------------
// Kernel 0: weight prep (unchanged from r12).
// ---------------------------------------------------------------------------
__global__ __launch_bounds__(64) void wprep(
    const float* __restrict__ wgh, const float* __restrict__ wzx,
    const float* __restrict__ wzm, const float* __restrict__ wrx,
    const float* __restrict__ wrm, const float* __restrict__ whx,
    const float* __restrict__ whm, const float* __restrict__ bgh,
    const float* __restrict__ bz, const float* __restrict__ br,
    const float* __restrict__ bh) {
  const int g = blockIdx.x, l = threadIdx.x;
  if (g < 112) {
    const float* mats[7] = {wgh, wzx, wzm, wrx, wrm, whx, whm};
    const int mat = g >> 4, sub = g & 15, ct = sub >> 1, tau = sub & 1;
    const float* W = mats[mat];
    const int base = ((mat * 8 + ct) * 2 + tau) * 512 + l * 8;
#pragma unroll
    for (int j = 0; j < 8; ++j) {
      const int k = 8 * (l >> 4) + j + 32 * tau;
      const int col = ct * 16 + (l & 15);
      g_W16[base + j] =
          __builtin_bit_cast(unsigned short, __float2half(W[k * 128 + col]));
    }
  } else {
    const int c = (g - 112) * 64 + l;
    float v = (c < 128)   ? bgh[c]
              : (c < 256) ? bz[c - 128]
              : (c < 384) ? br[c - 256]
                          : bh[c - 384];
    g_bias[c] = v;
  }
}

// ---------------------------------------------------------------------------
// Kernel 1 (unchanged from r10/r12): MFMA pre-activations, swapped operands,
// direct 8B stores. A layout [row][4 gates][128] fp16, [G,z,r,h], G pre-exp'd.
// ---------------------------------------------------------------------------
__global__ __launch_bounds__(256) void grud_pre_mfma(
    const float* __restrict__ values, const float* __restrict__ masks,
    const float* __restrict__ deltas, const float* __restrict__ emean,
    const float* __restrict__ locf, const float* __restrict__ w_gamma_x,
    const float* __restrict__ b_gamma_x, __half* __restrict__ A) {
  __shared__ __align__(16) char plds[25344];
  float* c_wg = (float*)(plds + 24576);
  float* c_bg = (float*)(plds + 24832);
  float* c_mn = (float*)(plds + 25088);

  const int tid = threadIdx.x;
  const int rowbase = blockIdx.x * 64;

  if (tid < 64) c_wg[tid] = w_gamma_x[tid];
  else if (tid < 128) c_bg[tid - 64] = b_gamma_x[tid - 64];
  else if (tid < 192) c_mn[tid - 128] = emean[tid - 128];
  __syncthreads();

  {
    const int r = tid >> 2;
    const int sp = tid & 3;
    const int swz = (r & 7) << 4;
#pragma unroll
    for (int ss = 0; ss < 2; ++ss) {
      const int s = sp + 4 * ss;
      const int k0 = 8 * s;
      const size_t gb = (size_t)(rowbase + r) * 64 + k0;
      const float4* vp = (const float4*)(values + gb);
      const float4* mp = (const float4*)(masks + gb);
      const float4* dp = (const float4*)(deltas + gb);
      const float4* lp = (const float4*)(locf + gb);
      float4 v0 = vp[0], v1 = vp[1], m0 = mp[0], m1 = mp[1];
      float4 d0 = dp[0], d1 = dp[1], l0 = lp[0], l1 = lp[1];
      float vv[8] = {v0.x, v0.y, v0.z, v0.w, v1.x, v1.y, v1.z, v1.w};
      float mm[8] = {m0.x, m0.y, m0.z, m0.w, m1.x, m1.y, m1.z, m1.w};
      float dd[8] = {d0.x, d0.y, d0.z, d0.w, d1.x, d1.y, d1.z, d1.w};
      float ll[8] = {l0.x, l0.y, l0.z, l0.w, l1.x, l1.y, l1.z, l1.w};
      s16x8 xe_, mv_, dl_;
#pragma unroll
      for (int j = 0; j < 8; ++j) {
        const int d_ = k0 + j;
        float gx = __expf(-fmaxf(c_wg[d_] * dd[j] + c_bg[d_], 0.f));
        float xo = mm[j] * vv[j] +
                   (1.f - mm[j]) * (gx * ll[j] + (1.f - gx) * c_mn[d_]);
        xe_[j] = __builtin_bit_cast(short, __float2half(xo));
        mv_[j] = __builtin_bit_cast(short, __float2half(mm[j]));
        dl_[j] = __builtin_bit_cast(short, __float2half(dd[j]));
      }
      const int ta = r * 128 + ((s * 16) ^ swz);
      *(s16x8*)(plds + ta) = xe_;
      *(s16x8*)(plds + 8192 + ta) = mv_;
      *(s16x8*)(plds + 16384 + ta) = dl_;
    }
  }
  __syncthreads();

  const int l = tid & 63;
  const int rt = tid >> 6;
  f16x8v xe0, xe1, mm0, mm1, dl0, dl1;
  {
    const int r = rt * 16 + (l & 15);
    const int swz = (r & 7) << 4;
    const int s0 = ((l >> 4) * 16) ^ swz;
    const int s1 = (((l >> 4) + 4) * 16) ^ swz;
    xe0 = *(const f16x8v*)(plds + r * 128 + s0);
    xe1 = *(const f16x8v*)(plds + r * 128 + s1);
    mm0 = *(const f16x8v*)(plds + 8192 + r * 128 + s0);
    mm1 = *(const f16x8v*)(plds + 8192 + r * 128 + s1);
    dl0 = *(const f16x8v*)(plds + 16384 + r * 128 + s0);
    dl1 = *(const f16x8v*)(plds + 16384 + r * 128 + s1);
  }

  const s16x8* Wb = (const s16x8*)g_W16;
  const int cj = (l >> 4) * 4;
  const int row = rowbase + rt * 16 + (l & 15);
  unsigned short* Aout = (unsigned short*)A + (size_t)row * 512;
#pragma unroll 4
  for (int ct = 0; ct < 32; ++ct) {
    const int g = ct >> 3, ctl = ct & 7;
    f32x4 acc = {0.f, 0.f, 0.f, 0.f};
    if (g == 0) {
      s16x8 B0 = Wb[(ctl * 2 + 0) * 64 + l];
      s16x8 B1 = Wb[(ctl * 2 + 1) * 64 + l];
      acc = MFH2(B0, dl0, acc);
      acc = MFH2(B1, dl1, acc);
    } else {
      const int mx = 2 * g - 1, mmat = 2 * g;
      s16x8 Bx0 = Wb[((mx * 8 + ctl) * 2 + 0) * 64 + l];
      s16x8 Bx1 = Wb[((mx * 8 + ctl) * 2 + 1) * 64 + l];
      s16x8 Bm0 = Wb[((mmat * 8 + ctl) * 2 + 0) * 64 + l];
      s16x8 Bm1 = Wb[((mmat * 8 + ctl) * 2 + 1) * 64 + l];
      acc = MFH2(Bx0, xe0, acc);
      acc = MFH2(Bx1, xe1, acc);
      acc = MFH2(Bm0, mm0, acc);
      acc = MFH2(Bm1, mm1, acc);
    }
    const f32x4 bv = *(const f32x4*)(g_bias + ct * 16 + cj);
    h16x4 outv;
#pragma unroll
    for (int j = 0; j < 4; ++j) {
      float v = acc[j] + bv[j];
      if (ct < 8) v = __expf(-fmaxf(v, 0.f));
      outv[j] = (_Float16)v;
    }
    *(h16x4*)(Aout + g * 128 + ctl * 16 + cj) = outv;
  }
}

// ---------------------------------------------------------------------------
// Kernel 2: MFMA recurrence, TWO independent 16-batch groups per block
// (BB=32, 8 blocks, 512 threads / 8 waves). The two groups share weights,
// barriers, and instruction stream; their dependency chains are independent,
// so each group's latency (LDS read, MFMA chain, exp) hides under the
// other's issue. Per group: same verified structure as r12 (acc-init from
// fp16 A rows, lgkm-only barriers, B-frag LDS layout with bijective scatter
// (w,b,q) -> (w>>1)*1024 + (b+16*((2w+(q>>1))&3))*16 + 8*(q&1)).
// LDS: group A h@0 rh@4096; group B h@8192 rh@12288.
// ---------------------------------------------------------------------------
#define STEP(T0, CUR, NXT)                                                  \
  do {                                                                      \
    const int t_ = (T0);                                                    \
    f32x4 DzA = {(float)CUR[1][0], (float)CUR[1][1],                        \
                 (float)CUR[1][2], (float)CUR[1][3]};                       \
    f32x4 DrA = {(float)CUR[2][0], (float)CUR[2][1],                        \
                 (float)CUR[2][2], (float)CUR[2][3]};                       \
    f32x4 DhA = {(float)CUR[3][0], (float)CUR[3][1],                        \
                 (float)CUR[3][2], (float)CUR[3][3]};                       \
    f32x4 DzB = {(float)CUR[5][0], (float)CUR[5][1],                        \
                 (float)CUR[5][2], (float)CUR[5][3]};                       \
    f32x4 DrB = {(float)CUR[6][0], (float)CUR[6][1],                        \
                 (float)CUR[6][2], (float)CUR[6][3]};                       \
    f32x4 DhB = {(float)CUR[7][0], (float)CUR[7][1],                        \
                 (float)CUR[7][2], (float)CUR[7][3]};                       \
    { /* re-issue CUR <- rows t+4, both groups */                           \
      const int t4 = (t_ + 4 < T_) ? t_ + 4 : T_ - 1;                       \
      const size_t rA = ((size_t)bgA * T_ + t4) * 128 + ci;                 \
      const size_t rB = ((size_t)bgB * T_ + t4) * 128 + ci;                 \
      CUR[0] = Arows[rA];       CUR[1] = Arows[rA + 32];                    \
      CUR[2] = Arows[rA + 64];  CUR[3] = Arows[rA + 96];                    \
      CUR[4] = Arows[rB];       CUR[5] = Arows[rB + 32];                    \
      CUR[6] = Arows[rB + 64];  CUR[7] = Arows[rB + 96];                    \
    }                                                                       \
    {                                                                       \
      s16x8 hA0 = *(const s16x8*)(lds + off_rd[0]);                         \
      s16x8 hA1 = *(const s16x8*)(lds + off_rd[1]);                         \
      s16x8 hA2 = *(const s16x8*)(lds + off_rd[2]);                         \
      s16x8 hA3 = *(const s16x8*)(lds + off_rd[3]);                         \
      s16x8 hB0 = *(const s16x8*)(lds + 8192 + off_rd[0]);                  \
      s16x8 hB1 = *(const s16x8*)(lds + 8192 + off_rd[1]);                  \
      s16x8 hB2 = *(const s16x8*)(lds + 8192 + off_rd[2]);                  \
      s16x8 hB3 = *(const s16x8*)(lds + 8192 + off_rd[3]);                  \
      DzA = MFH(wzf[0], hA0, DzA); DzB = MFH(wzf[0], hB0, DzB);             \
      DrA = MFH(wrf[0], hA0, DrA); DrB = MFH(wrf[0], hB0, DrB);             \
      DzA = MFH(wzf[1], hA1, DzA); DzB = MFH(wzf[1], hB1, DzB);             \
      DrA = MFH(wrf[1], hA1, DrA); DrB = MFH(wrf[1], hB1, DrB);             \
      DzA = MFH(wzf[2], hA2, DzA); DzB = MFH(wzf[2], hB2, DzB);             \
      DrA = MFH(wrf[2], hA2, DrA); DrB = MFH(wrf[2], hB2, DrB);             \
      DzA = MFH(wzf[3], hA3, DzA); DzB = MFH(wzf[3], hB3, DzB);             \
      DrA = MFH(wrf[3], hA3, DrA); DrB = MFH(wrf[3], hB3, DrB);             \
    }                                                                       \
    f32x4 zzA, zzB;                                                         \
    {                                                                       \
      union { fp16x2 h2[2]; s16x4 v; } uA, uB;                              \
      float a0 = fsig(DrA[0]) * hscA[0], a1 = fsig(DrA[1]) * hscA[1];       \
      float a2 = fsig(DrA[2]) * hscA[2], a3 = fsig(DrA[3]) * hscA[3];       \
      float b0_ = fsig(DrB[0]) * hscB[0], b1_ = fsig(DrB[1]) * hscB[1];     \
      float b2_ = fsig(DrB[2]) * hscB[2], b3_ = fsig(DrB[3]) * hscB[3];     \
      zzA[0] = fsig(DzA[0]); zzA[1] = fsig(DzA[1]);                         \
      zzA[2] = fsig(DzA[2]); zzA[3] = fsig(DzA[3]);                         \
      zzB[0] = fsig(DzB[0]); zzB[1] = fsig(DzB[1]);                         \
      zzB[2] = fsig(DzB[2]); zzB[3] = fsig(DzB[3]);                         \
      uA.h2[0] = __builtin_amdgcn_cvt_pkrtz(a0, a1);                        \
      uA.h2[1] = __builtin_amdgcn_cvt_pkrtz(a2, a3);                        \
      uB.h2[0] = __builtin_amdgcn_cvt_pkrtz(b0_, b1_);                      \
      uB.h2[1] = __builtin_amdgcn_cvt_pkrtz(b2_, b3_);                      \
      *(s16x4*)(lds + 4096 + off_wr) = uA.v;                                \
      *(s16x4*)(lds + 12288 + off_wr) = uB.v;                               \
    }                                                                       \
    BAR();                                                                  \
    {                                                                       \
      s16x8 pA0 = *(const s16x8*)(lds + 4096 + off_rd[0]);                  \
      s16x8 pA1 = *(const s16x8*)(lds + 4096 + off_rd[1]);                  \
      s16x8 pA2 = *(const s16x8*)(lds + 4096 + off_rd[2]);                  \
      s16x8 pA3 = *(const s16x8*)(lds + 4096 + off_rd[3]);                  \
      s16x8 pB0 = *(const s16x8*)(lds + 12288 + off_rd[0]);                 \
      s16x8 pB1 = *(const s16x8*)(lds + 12288 + off_rd[1]);                 \
      s16x8 pB2 = *(const s16x8*)(lds + 12288 + off_rd[2]);                 \
      s16x8 pB3 = *(const s16x8*)(lds + 12288 + off_rd[3]);                 \
      DhA = MFH(whf[0], pA0, DhA); DhB = MFH(whf[0], pB0, DhB);             \
      DhA = MFH(whf[1], pA1, DhA); DhB = MFH(whf[1], pB1, DhB);             \
      DhA = MFH(whf[2], pA2, DhA); DhB = MFH(whf[2], pB2, DhB);             \
      DhA = MFH(whf[3], pA3, DhA); DhB = MFH(whf[3], pB3, DhB);             \
    }                                                                       \
    {                                                                       \
      f32x4 hnA, hnB;                                                       \
      union { fp16x2 h2[2]; s16x4 v; } uA, uB;                              \
      _Pragma("unroll")                                                     \
      for (int j = 0; j < 4; ++j) {                                         \
        float htA = ftanh(DhA[j]);                                          \
        float ha = hscA[j] + zzA[j] * (htA - hscA[j]);                      \
        hnA[j] = ha;                                                        \
        hscA[j] = ha * (float)NXT[0][j];                                    \
        float htB = ftanh(DhB[j]);                                          \
        float hb = hscB[j] + zzB[j] * (htB - hscB[j]);                      \
        hnB[j] = hb;                                                        \
        hscB[j] = hb * (float)NXT[4][j];                                    \
      }                                                                     \
      uA.h2[0] = __builtin_amdgcn_cvt_pkrtz(hscA[0], hscA[1]);              \
      uA.h2[1] = __builtin_amdgcn_cvt_pkrtz(hscA[2], hscA[3]);              \
      uB.h2[0] = __builtin_amdgcn_cvt_pkrtz(hscB[0], hscB[1]);              \
      uB.h2[1] = __builtin_amdgcn_cvt_pkrtz(hscB[2], hscB[3]);              \
      *(s16x4*)(lds + off_wr) = uA.v;                                       \
      *(s16x4*)(lds + 8192 + off_wr) = uB.v;                                \
      *(f32x4*)(hid + ((size_t)bgA * T_ + t_) * H_ + cb) = hnA;             \
      *(f32x4*)(hid + ((size_t)bgB * T_ + t_) * H_ + cb) = hnB;             \
      if (t_ == T_ - 1) {                                                   \
        *(f32x4*)(hlast + (size_t)bgA * H_ + cb) = hnA;                     \
        *(f32x4*)(hlast + (size_t)bgB * H_ + cb) = hnB;                     \
      }                                                                     \
    }                                                                       \
    BAR();                                                                  \
  } while (0)

__global__ __launch_bounds__(512, 1) void grud_rec_mfma(
    const __half* __restrict__ A, const float* __restrict__ w_zh,
    const float* __restrict__ w_rh, const float* __restrict__ w_hh,
    float* __restrict__ hid, float* __restrict__ hlast) {
  const int tid = threadIdx.x;
  const int w = tid >> 6;
  const int lane = tid & 63;
  const int b = lane & 15;
  const int q = lane >> 4;
  const int cb = w * 16 + q * 4;
  const int bgA = blockIdx.x * BB + b;
  const int bgB = bgA + 16;

  __shared__ __align__(16) char lds[16384];

  // fp16 A-frags (shared by both groups): frag tau, reg j = W[q*8+j+32t][w*16+b]
  s16x8 wzf[4], wrf[4], whf[4];
#pragma unroll
  for (int tau = 0; tau < 4; ++tau) {
    s16x8 az, ar, ah;
#pragma unroll
    for (int j = 0; j < 8; ++j) {
      const int k = q * 8 + j + 32 * tau;
      az[j] = __builtin_bit_cast(short, (_Float16)w_zh[k * H_ + w * 16 + b]);
      ar[j] = __builtin_bit_cast(short, (_Float16)w_rh[k * H_ + w * 16 + b]);
      ah[j] = __builtin_bit_cast(short, (_Float16)w_hh[k * H_ + w * 16 + b]);
    }
    wzf[tau] = az; wrf[tau] = ar; whf[tau] = ah;
  }

  for (int i = tid; i < 16384 / 16; i += 512)
    ((f32x4*)lds)[i] = f32x4{0.f, 0.f, 0.f, 0.f};

  int off_rd[4];
#pragma unroll
  for (int tau = 0; tau < 4; ++tau) off_rd[tau] = tau * 1024 + lane * 16;
  const int off_wr =
      (w >> 1) * 1024 + (b + 16 * ((2 * w + (q >> 1)) & 3)) * 16 + 8 * (q & 1);

  const h16x4* Arows = (const h16x4*)A;
  const int ci = cb >> 2;

  // 4 named prefetch buffers x [A:G,z,r,h | B:G,z,r,h]
  h16x4 b0[8], b1[8], b2[8], b3[8];
#pragma unroll
  for (int t0 = 0; t0 < 4; ++t0) {
    h16x4* dst = (t0 == 0) ? b0 : (t0 == 1) ? b1 : (t0 == 2) ? b2 : b3;
    const size_t rA = ((size_t)bgA * T_ + t0) * 128 + ci;
    const size_t rB = ((size_t)bgB * T_ + t0) * 128 + ci;
    dst[0] = Arows[rA];       dst[1] = Arows[rA + 32];
    dst[2] = Arows[rA + 64];  dst[3] = Arows[rA + 96];
    dst[4] = Arows[rB];       dst[5] = Arows[rB + 32];
    dst[6] = Arows[rB + 64];  dst[7] = Arows[rB + 96];
  }
  f32x4 hscA = {0.f, 0.f, 0.f, 0.f}, hscB = {0.f, 0.f, 0.f, 0.f};
  __syncthreads();

  for (int tp = 0; tp < T_; tp += 4) {
    STEP(tp + 0, b0, b1);
    STEP(tp + 1, b1, b2);
    STEP(tp + 2, b2, b3);
    STEP(tp + 3, b3, b0);
  }
}

extern "C" void kernel_launch(void* const* d_in, const int* in_sizes, int n_in,
                              void* d_out, int out_size, void* d_ws, size_t ws_size,
                              hipStream_t stream) {
  const float* values = (const float*)d_in[0];
  const float* masks = (const float*)d_in[1];
  const float* deltas = (const float*)d_in[2];
  const float* emean = (const float*)d_in[3];
  const float* locf = (const float*)d_in[4];
  const float* w_gamma_x = (const float*)d_in[5];
  const float* w_gamma_h = (const float*)d_in[6];
  const float* w_rx = (const float*)d_in[7];
  const float* w_rh = (const float*)d_in[8];
  const float* w_rm = (const float*)d_in[9];
  const float* w_zx = (const float*)d_in[10];
  const float* w_zh = (const float*)d_in[11];
  const float* w_zm = (const float*)d_in[12];
  const float* w_hx = (const float*)d_in[13];
  const float* w_hh = (const float*)d_in[14];
  const float* w_hm = (const float*)d_in[15];
  const float* b_gamma_x = (const float*)d_in[16];
  const float* b_gamma_h = (const float*)d_in[17];
  const float* b_r = (const float*)d_in[18];
  const float* b_z = (const float*)d_in[19];
  const float* b_h = (const float*)d_in[20];

  float* hid = (float*)d_out;
  float* hlast = hid + (size_t)B_ * T_ * H_;
  __half* A = (__half*)d_ws;

  wprep<<<dim3(120), dim3(64), 0, stream>>>(
      w_gamma_h, w_zx, w_zm, w_rx, w_rm, w_hx, w_hm, b_gamma_h, b_z, b_r, b_h);
  grud_pre_mfma<<<dim3(B_ * T_ / 64), dim3(256), 0, stream>>>(
      values, masks, deltas, emean, locf, w_gamma_x, b_gamma_x, A);
  grud_rec_mfma<<<dim3(B_ / BB), dim3(512), 0, stream>>>(A, w_zh, w_rh, w_hh,
                                                         hid, hlast);
}

// Round 14
// 629.257 us; speedup vs baseline: 1.8936x; 1.8936x over previous
//
#include <hip/hip_runtime.h>
#include <hip/hip_fp16.h>

#define B_ 256
#define T_ 512
#define D_ 64
#define H_ 128
#define BB 16  // batches per recurrent block

typedef float f32x4 __attribute__((ext_vector_type(4)));
typedef short s16x4 __attribute__((ext_vector_type(4)));
typedef short s16x8 __attribute__((ext_vector_type(8)));
typedef __fp16 fp16x2 __attribute__((ext_vector_type(2)));
typedef _Float16 h16x4 __attribute__((ext_vector_type(4)));
typedef _Float16 f16x8v __attribute__((ext_vector_type(8)));

__device__ unsigned short g_W16[7 * 8 * 2 * 512];  // fp16 frag-ordered weights
__device__ float g_bias[512];                      // [G,z,r,h] biases

__device__ inline float fsig(float x) {
  return __builtin_amdgcn_rcpf(1.f + __expf(-x));
}
__device__ inline float ftanh(float x) {
  return 1.f - 2.f * __builtin_amdgcn_rcpf(1.f + __expf(2.f * x));
}
// fp16 MFMA, both operands as raw 16-bit fragments
__device__ __forceinline__ f32x4 MFH(s16x8 a, s16x8 b, f32x4 c) {
  return __builtin_amdgcn_mfma_f32_16x16x32_f16(
      __builtin_bit_cast(f16x8v, a), __builtin_bit_cast(f16x8v, b), c, 0, 0, 0);
}
__device__ __forceinline__ f32x4 MFH2(s16x8 wfrag, f16x8v xfrag, f32x4 c) {
  return __builtin_amdgcn_mfma_f32_16x16x32_f16(
      __builtin_bit_cast(f16x8v, wfrag), xfrag, c, 0, 0, 0);
}

// Barrier draining ONLY LDS ops: global loads/stores stay in flight.
#define BAR()                                              \
  do {                                                     \
    asm volatile("s_waitcnt lgkmcnt(0)" ::: "memory");     \
    __builtin_amdgcn_s_barrier();                          \
  } while (0)

// ---------------------------------------------------------------------------
// Kernel 0: weight prep (unchanged from r12).
// ---------------------------------------------------------------------------
__global__ __launch_bounds__(64) void wprep(
    const float* __restrict__ wgh, const float* __restrict__ wzx,
    const float* __restrict__ wzm, const float* __restrict__ wrx,
    const float* __restrict__ wrm, const float* __restrict__ whx,
    const float* __restrict__ whm, const float* __restrict__ bgh,
    const float* __restrict__ bz, const float* __restrict__ br,
    const float* __restrict__ bh) {
  const int g = blockIdx.x, l = threadIdx.x;
  if (g < 112) {
    const float* mats[7] = {wgh, wzx, wzm, wrx, wrm, whx, whm};
    const int mat = g >> 4, sub = g & 15, ct = sub >> 1, tau = sub & 1;
    const float* W = mats[mat];
    const int base = ((mat * 8 + ct) * 2 + tau) * 512 + l * 8;
#pragma unroll
    for (int j = 0; j < 8; ++j) {
      const int k = 8 * (l >> 4) + j + 32 * tau;
      const int col = ct * 16 + (l & 15);
      g_W16[base + j] =
          __builtin_bit_cast(unsigned short, __float2half(W[k * 128 + col]));
    }
  } else {
    const int c = (g - 112) * 64 + l;
    float v = (c < 128)   ? bgh[c]
              : (c < 256) ? bz[c - 128]
              : (c < 384) ? br[c - 256]
                          : bh[c - 384];
    g_bias[c] = v;
  }
}

// ---------------------------------------------------------------------------
// Kernel 1 (unchanged from r10/r12): MFMA pre-activations, swapped operands,
// direct 8B stores. A layout [row][4 gates][128] fp16, [G,z,r,h], G pre-exp'd.
// ---------------------------------------------------------------------------
__global__ __launch_bounds__(256) void grud_pre_mfma(
    const float* __restrict__ values, const float* __restrict__ masks,
    const float* __restrict__ deltas, const float* __restrict__ emean,
    const float* __restrict__ locf, const float* __restrict__ w_gamma_x,
    const float* __restrict__ b_gamma_x, __half* __restrict__ A) {
  __shared__ __align__(16) char plds[25344];
  float* c_wg = (float*)(plds + 24576);
  float* c_bg = (float*)(plds + 24832);
  float* c_mn = (float*)(plds + 25088);

  const int tid = threadIdx.x;
  const int rowbase = blockIdx.x * 64;

  if (tid < 64) c_wg[tid] = w_gamma_x[tid];
  else if (tid < 128) c_bg[tid - 64] = b_gamma_x[tid - 64];
  else if (tid < 192) c_mn[tid - 128] = emean[tid - 128];
  __syncthreads();

  {
    const int r = tid >> 2;
    const int sp = tid & 3;
    const int swz = (r & 7) << 4;
#pragma unroll
    for (int ss = 0; ss < 2; ++ss) {
      const int s = sp + 4 * ss;
      const int k0 = 8 * s;
      const size_t gb = (size_t)(rowbase + r) * 64 + k0;
      const float4* vp = (const float4*)(values + gb);
      const float4* mp = (const float4*)(masks + gb);
      const float4* dp = (const float4*)(deltas + gb);
      const float4* lp = (const float4*)(locf + gb);
      float4 v0 = vp[0], v1 = vp[1], m0 = mp[0], m1 = mp[1];
      float4 d0 = dp[0], d1 = dp[1], l0 = lp[0], l1 = lp[1];
      float vv[8] = {v0.x, v0.y, v0.z, v0.w, v1.x, v1.y, v1.z, v1.w};
      float mm[8] = {m0.x, m0.y, m0.z, m0.w, m1.x, m1.y, m1.z, m1.w};
      float dd[8] = {d0.x, d0.y, d0.z, d0.w, d1.x, d1.y, d1.z, d1.w};
      float ll[8] = {l0.x, l0.y, l0.z, l0.w, l1.x, l1.y, l1.z, l1.w};
      s16x8 xe_, mv_, dl_;
#pragma unroll
      for (int j = 0; j < 8; ++j) {
        const int d_ = k0 + j;
        float gx = __expf(-fmaxf(c_wg[d_] * dd[j] + c_bg[d_], 0.f));
        float xo = mm[j] * vv[j] +
                   (1.f - mm[j]) * (gx * ll[j] + (1.f - gx) * c_mn[d_]);
        xe_[j] = __builtin_bit_cast(short, __float2half(xo));
        mv_[j] = __builtin_bit_cast(short, __float2half(mm[j]));
        dl_[j] = __builtin_bit_cast(short, __float2half(dd[j]));
      }
      const int ta = r * 128 + ((s * 16) ^ swz);
      *(s16x8*)(plds + ta) = xe_;
      *(s16x8*)(plds + 8192 + ta) = mv_;
      *(s16x8*)(plds + 16384 + ta) = dl_;
    }
  }
  __syncthreads();

  const int l = tid & 63;
  const int rt = tid >> 6;
  f16x8v xe0, xe1, mm0, mm1, dl0, dl1;
  {
    const int r = rt * 16 + (l & 15);
    const int swz = (r & 7) << 4;
    const int s0 = ((l >> 4) * 16) ^ swz;
    const int s1 = (((l >> 4) + 4) * 16) ^ swz;
    xe0 = *(const f16x8v*)(plds + r * 128 + s0);
    xe1 = *(const f16x8v*)(plds + r * 128 + s1);
    mm0 = *(const f16x8v*)(plds + 8192 + r * 128 + s0);
    mm1 = *(const f16x8v*)(plds + 8192 + r * 128 + s1);
    dl0 = *(const f16x8v*)(plds + 16384 + r * 128 + s0);
    dl1 = *(const f16x8v*)(plds + 16384 + r * 128 + s1);
  }

  const s16x8* Wb = (const s16x8*)g_W16;
  const int cj = (l >> 4) * 4;
  const int row = rowbase + rt * 16 + (l & 15);
  unsigned short* Aout = (unsigned short*)A + (size_t)row * 512;
#pragma unroll 4
  for (int ct = 0; ct < 32; ++ct) {
    const int g = ct >> 3, ctl = ct & 7;
    f32x4 acc = {0.f, 0.f, 0.f, 0.f};
    if (g == 0) {
      s16x8 B0 = Wb[(ctl * 2 + 0) * 64 + l];
      s16x8 B1 = Wb[(ctl * 2 + 1) * 64 + l];
      acc = MFH2(B0, dl0, acc);
      acc = MFH2(B1, dl1, acc);
    } else {
      const int mx = 2 * g - 1, mmat = 2 * g;
      s16x8 Bx0 = Wb[((mx * 8 + ctl) * 2 + 0) * 64 + l];
      s16x8 Bx1 = Wb[((mx * 8 + ctl) * 2 + 1) * 64 + l];
      s16x8 Bm0 = Wb[((mmat * 8 + ctl) * 2 + 0) * 64 + l];
      s16x8 Bm1 = Wb[((mmat * 8 + ctl) * 2 + 1) * 64 + l];
      acc = MFH2(Bx0, xe0, acc);
      acc = MFH2(Bx1, xe1, acc);
      acc = MFH2(Bm0, mm0, acc);
      acc = MFH2(Bm1, mm1, acc);
    }
    const f32x4 bv = *(const f32x4*)(g_bias + ct * 16 + cj);
    h16x4 outv;
#pragma unroll
    for (int j = 0; j < 4; ++j) {
      float v = acc[j] + bv[j];
      if (ct < 8) v = __expf(-fmaxf(v, 0.f));
      outv[j] = (_Float16)v;
    }
    *(h16x4*)(Aout + g * 128 + ctl * 16 + cj) = outv;
  }
}

// ---------------------------------------------------------------------------
// Kernel 2: MFMA recurrence (r12 structure — 16 blocks x 16 batches, 512 thr,
// 8 waves, fp16, acc-init, lgkm-only barriers, bijective B-frag scatter).
// r14 changes: unconditional-prefetch main loop (no min() select in the
// prefetch address -> strength-reduced addressing), clamped epilogue for the
// last 8 steps, s_setprio around MFMA clusters, hlast handled in epilogue.
// ---------------------------------------------------------------------------
#define STEP_CORE(T0, CUR, NXT, T4)                                         \
  do {                                                                      \
    const int t_ = (T0);                                                    \
    f32x4 Dz0 = {(float)CUR[1][0], (float)CUR[1][1],                        \
                 (float)CUR[1][2], (float)CUR[1][3]};                       \
    f32x4 Dr0 = {(float)CUR[2][0], (float)CUR[2][1],                        \
                 (float)CUR[2][2], (float)CUR[2][3]};                       \
    f32x4 Dh0 = {(float)CUR[3][0], (float)CUR[3][1],                        \
                 (float)CUR[3][2], (float)CUR[3][3]};                       \
    { /* re-issue CUR <- rows T4 (no clamp in main loop) */                 \
      const size_t r = ((size_t)bg * T_ + (T4)) * 128 + ci;                 \
      CUR[0] = Arows[r];       CUR[1] = Arows[r + 32];                      \
      CUR[2] = Arows[r + 64];  CUR[3] = Arows[r + 96];                      \
    }                                                                       \
    f32x4 Dz1 = {0, 0, 0, 0}, Dr1 = {0, 0, 0, 0};                           \
    {                                                                       \
      s16x8 bh0 = *(const s16x8*)(h_bf + off_rd[0]);                        \
      s16x8 bh1 = *(const s16x8*)(h_bf + off_rd[1]);                        \
      s16x8 bh2 = *(const s16x8*)(h_bf + off_rd[2]);                        \
      s16x8 bh3 = *(const s16x8*)(h_bf + off_rd[3]);                        \
      __builtin_amdgcn_s_setprio(1);                                        \
      Dz0 = MFH(wzf[0], bh0, Dz0); Dr0 = MFH(wrf[0], bh0, Dr0);             \
      Dz1 = MFH(wzf[2], bh2, Dz1); Dr1 = MFH(wrf[2], bh2, Dr1);             \
      Dz0 = MFH(wzf[1], bh1, Dz0); Dr0 = MFH(wrf[1], bh1, Dr0);             \
      Dz1 = MFH(wzf[3], bh3, Dz1); Dr1 = MFH(wrf[3], bh3, Dr1);             \
      __builtin_amdgcn_s_setprio(0);                                        \
    }                                                                       \
    f32x4 zz;                                                               \
    {                                                                       \
      float r0_ = fsig(Dr0[0] + Dr1[0]) * hsc[0];                           \
      float r1_ = fsig(Dr0[1] + Dr1[1]) * hsc[1];                           \
      float r2_ = fsig(Dr0[2] + Dr1[2]) * hsc[2];                           \
      float r3_ = fsig(Dr0[3] + Dr1[3]) * hsc[3];                           \
      zz[0] = fsig(Dz0[0] + Dz1[0]); zz[1] = fsig(Dz0[1] + Dz1[1]);         \
      zz[2] = fsig(Dz0[2] + Dz1[2]); zz[3] = fsig(Dz0[3] + Dz1[3]);         \
      union { fp16x2 h2[2]; s16x4 v; } u;                                   \
      u.h2[0] = __builtin_amdgcn_cvt_pkrtz(r0_, r1_);                       \
      u.h2[1] = __builtin_amdgcn_cvt_pkrtz(r2_, r3_);                       \
      *(s16x4*)(rh_bf + off_wr) = u.v;                                      \
    }                                                                       \
    BAR();                                                                  \
    f32x4 Dh1 = {0, 0, 0, 0};                                               \
    {                                                                       \
      s16x8 p0 = *(const s16x8*)(rh_bf + off_rd[0]);                        \
      s16x8 p1 = *(const s16x8*)(rh_bf + off_rd[1]);                        \
      s16x8 p2 = *(const s16x8*)(rh_bf + off_rd[2]);                        \
      s16x8 p3 = *(const s16x8*)(rh_bf + off_rd[3]);                        \
      __builtin_amdgcn_s_setprio(1);                                        \
      Dh0 = MFH(whf[0], p0, Dh0); Dh1 = MFH(whf[2], p2, Dh1);               \
      Dh0 = MFH(whf[1], p1, Dh0); Dh1 = MFH(whf[3], p3, Dh1);               \
      __builtin_amdgcn_s_setprio(0);                                        \
    }                                                                       \
    f32x4 hnv, hgv;                                                         \
    _Pragma("unroll")                                                       \
    for (int j = 0; j < 4; ++j) {                                           \
      float ht = ftanh(Dh0[j] + Dh1[j]);                                    \
      float hn = hsc[j] + zz[j] * (ht - hsc[j]);                            \
      hnv[j] = hn;                                                          \
      float hg = hn * (float)NXT[0][j]; /* fold gamma_h(t+1) */             \
      hgv[j] = hg;                                                          \
      hsc[j] = hg;                                                          \
    }                                                                       \
    {                                                                       \
      union { fp16x2 h2[2]; s16x4 v; } u;                                   \
      u.h2[0] = __builtin_amdgcn_cvt_pkrtz(hgv[0], hgv[1]);                 \
      u.h2[1] = __builtin_amdgcn_cvt_pkrtz(hgv[2], hgv[3]);                 \
      *(s16x4*)(h_bf + off_wr) = u.v;                                       \
    }                                                                       \
    *(f32x4*)(hid + ((size_t)bg * T_ + t_) * H_ + cb) = hnv;                \
    lasth = hnv;                                                            \
    BAR();                                                                  \
  } while (0)

#define STEP(T0, CUR, NXT) STEP_CORE(T0, CUR, NXT, (T0) + 4)
#define STEPC(T0, CUR, NXT) \
  STEP_CORE(T0, CUR, NXT, ((T0) + 4 < T_) ? (T0) + 4 : T_ - 1)

__global__ __launch_bounds__(512, 1) void grud_rec_mfma(
    const __half* __restrict__ A, const float* __restrict__ w_zh,
    const float* __restrict__ w_rh, const float* __restrict__ w_hh,
    float* __restrict__ hid, float* __restrict__ hlast) {
  const int tid = threadIdx.x;
  const int w = tid >> 6;
  const int lane = tid & 63;
  const int b = lane & 15;
  const int q = lane >> 4;
  const int cb = w * 16 + q * 4;
  const int bg = blockIdx.x * BB + b;

  __shared__ __align__(16) char lds[8192];
  char* h_bf = lds;
  char* rh_bf = lds + 4096;

  // fp16 A-frags: frag tau, reg j = W[q*8+j+32*tau][w*16+b]
  s16x8 wzf[4], wrf[4], whf[4];
#pragma unroll
  for (int tau = 0; tau < 4; ++tau) {
    s16x8 az, ar, ah;
#pragma unroll
    for (int j = 0; j < 8; ++j) {
      const int k = q * 8 + j + 32 * tau;
      az[j] = __builtin_bit_cast(short, (_Float16)w_zh[k * H_ + w * 16 + b]);
      ar[j] = __builtin_bit_cast(short, (_Float16)w_rh[k * H_ + w * 16 + b]);
      ah[j] = __builtin_bit_cast(short, (_Float16)w_hh[k * H_ + w * 16 + b]);
    }
    wzf[tau] = az; wrf[tau] = ar; whf[tau] = ah;
  }

  for (int i = tid; i < 8192 / 16; i += 512)
    ((f32x4*)lds)[i] = f32x4{0.f, 0.f, 0.f, 0.f};

  int off_rd[4];
#pragma unroll
  for (int tau = 0; tau < 4; ++tau) off_rd[tau] = tau * 1024 + lane * 16;
  const int off_wr =
      (w >> 1) * 1024 + (b + 16 * ((2 * w + (q >> 1)) & 3)) * 16 + 8 * (q & 1);

  const h16x4* Arows = (const h16x4*)A;
  const int ci = cb >> 2;

  h16x4 b0[4], b1[4], b2[4], b3[4];
  {
    const size_t r0 = ((size_t)bg * T_ + 0) * 128 + ci;
    b0[0] = Arows[r0]; b0[1] = Arows[r0 + 32];
    b0[2] = Arows[r0 + 64]; b0[3] = Arows[r0 + 96];
    const size_t r1 = ((size_t)bg * T_ + 1) * 128 + ci;
    b1[0] = Arows[r1]; b1[1] = Arows[r1 + 32];
    b1[2] = Arows[r1 + 64]; b1[3] = Arows[r1 + 96];
    const size_t r2 = ((size_t)bg * T_ + 2) * 128 + ci;
    b2[0] = Arows[r2]; b2[1] = Arows[r2 + 32];
    b2[2] = Arows[r2 + 64]; b2[3] = Arows[r2 + 96];
    const size_t r3 = ((size_t)bg * T_ + 3) * 128 + ci;
    b3[0] = Arows[r3]; b3[1] = Arows[r3 + 32];
    b3[2] = Arows[r3 + 64]; b3[3] = Arows[r3 + 96];
  }
  f32x4 hsc = {0.f, 0.f, 0.f, 0.f};
  f32x4 lasth = {0.f, 0.f, 0.f, 0.f};
  __syncthreads();

  // main loop: unconditional t+4 prefetch (addresses strength-reduce)
  for (int tp = 0; tp < T_ - 8; tp += 4) {
    STEP(tp + 0, b0, b1);
    STEP(tp + 1, b1, b2);
    STEP(tp + 2, b2, b3);
    STEP(tp + 3, b3, b0);
  }
  // epilogue: last 8 steps, clamped prefetch
  {
    const int tp = T_ - 8;
    STEPC(tp + 0, b0, b1);
    STEPC(tp + 1, b1, b2);
    STEPC(tp + 2, b2, b3);
    STEPC(tp + 3, b3, b0);
    STEPC(tp + 4, b0, b1);
    STEPC(tp + 5, b1, b2);
    STEPC(tp + 6, b2, b3);
    STEPC(tp + 7, b3, b0);
  }
  *(f32x4*)(hlast + (size_t)bg * H_ + cb) = lasth;
}

extern "C" void kernel_launch(void* const* d_in, const int* in_sizes, int n_in,
                              void* d_out, int out_size, void* d_ws, size_t ws_size,
                              hipStream_t stream) {
  const float* values = (const float*)d_in[0];
  const float* masks = (const float*)d_in[1];
  const float* deltas = (const float*)d_in[2];
  const float* emean = (const float*)d_in[3];
  const float* locf = (const float*)d_in[4];
  const float* w_gamma_x = (const float*)d_in[5];
  const float* w_gamma_h = (const float*)d_in[6];
  const float* w_rx = (const float*)d_in[7];
  const float* w_rh = (const float*)d_in[8];
  const float* w_rm = (const float*)d_in[9];
  const float* w_zx = (const float*)d_in[10];
  const float* w_zh = (const float*)d_in[11];
  const float* w_zm = (const float*)d_in[12];
  const float* w_hx = (const float*)d_in[13];
  const float* w_hh = (const float*)d_in[14];
  const float* w_hm = (const float*)d_in[15];
  const float* b_gamma_x = (const float*)d_in[16];
  const float* b_gamma_h = (const float*)d_in[17];
  const float* b_r = (const float*)d_in[18];
  const float* b_z = (const float*)d_in[19];
  const float* b_h = (const float*)d_in[20];

  float* hid = (float*)d_out;
  float* hlast = hid + (size_t)B_ * T_ * H_;
  __half* A = (__half*)d_ws;

  wprep<<<dim3(120), dim3(64), 0, stream>>>(
      w_gamma_h, w_zx, w_zm, w_rx, w_rm, w_hx, w_hm, b_gamma_h, b_z, b_r, b_h);
  grud_pre_mfma<<<dim3(B_ * T_ / 64), dim3(256), 0, stream>>>(
      values, masks, deltas, emean, locf, w_gamma_x, b_gamma_x, A);
  grud_rec_mfma<<<dim3(B_ / BB), dim3(512), 0, stream>>>(A, w_zh, w_rh, w_hh,
                                                         hid, hlast);
}